// Round 8
// baseline (78.885 us; speedup 1.0000x reference)
//
#include <hip/hip_runtime.h>
#include <math.h>

#define CC 128   // channels
#define NN 1024  // H*W
#define BTOT 32  // B*T
#define CP 152   // k_front LDS row stride (bf16 elems)
#define PSTs 40  // P column-buffer row stride (u16): 80B
#define CPA 136  // att_lds row stride (u16): 272B = 17*16
#define CQS 36   // conv_q row stride (f32): 144B = 9*16

typedef unsigned short u16;
typedef u16 u16x8 __attribute__((ext_vector_type(8)));
typedef u16 u16x4 __attribute__((ext_vector_type(4)));
typedef __bf16 bf16x8 __attribute__((ext_vector_type(8)));
typedef float f32x4 __attribute__((ext_vector_type(4)));

__device__ __forceinline__ u16 f2b(float f) {
    unsigned int u = __float_as_uint(f);
    u += 0x7FFFu + ((u >> 16) & 1u);   // RNE
    return (u16)(u >> 16);
}
__device__ __forceinline__ float b2f(u16 u) {
    return __uint_as_float(((unsigned int)u) << 16);
}

// ---------- MFMA helpers ----------
// A-frag: lane l holds A[16*ot + (l&15)][32*kk + 8*(l>>4) + j], j=0..7.
// B-frag: lane l holds B[16*nt + (l&15)][32*kk + 8*(l>>4) + j].
// C/D: col = l&15 (B row), row = (l>>4)*4 + r (+16*ot) (A row).
__device__ __forceinline__ void loadB(const u16* brow, int g, bf16x8 bfr[4]) {
#pragma unroll
    for (int kk = 0; kk < 4; ++kk)
        bfr[kk] = *(const bf16x8*)(brow + kk * 32 + g * 8);
}
__device__ __forceinline__ bf16x8 ldA(const u16* __restrict__ WB, int ot, int kk, int l) {
    return *(const bf16x8*)(WB + ((size_t)(ot * 4 + kk) * 64 + l) * 8);
}

// ---------- kernel 0: prep — pack We/Wd/Wf AND compose+pack Wqe/Wkd/Wvd ----------
__global__ __launch_bounds__(256) void k_prep(
    const float* __restrict__ We, const float* __restrict__ Wd,
    const float* __restrict__ Wf, const float* __restrict__ Wq,
    const float* __restrict__ Wk, const float* __restrict__ Wv,
    const float* __restrict__ be, const float* __restrict__ bd,
    u16* __restrict__ out, float* __restrict__ cvec)
{
    const int bid = blockIdx.x, t = threadIdx.x;
    if (bid < 24) {
        // plain pack: We->slot0, Wd->slot1, Wf->slot5
        const int gid = bid * 256 + t;       // 0..6143
        const int wi = gid >> 11;            // 0..2
        const float* W = (wi == 0) ? We : (wi == 1) ? Wd : Wf;
        const int slot = (wi == 2) ? 5 : wi;
        const int rem = gid & 2047;
        const int ot = rem >> 8, kk = (rem >> 6) & 3, l = rem & 63;
        const int row = ot * 16 + (l & 15), col = kk * 32 + (l >> 4) * 8;
        float4 a = *(const float4*)(W + row * CC + col);
        float4 b = *(const float4*)(W + row * CC + col + 4);
        u16x8 u;
        u[0] = f2b(a.x); u[1] = f2b(a.y); u[2] = f2b(a.z); u[3] = f2b(a.w);
        u[4] = f2b(b.x); u[5] = f2b(b.y); u[6] = f2b(b.z); u[7] = f2b(b.w);
        *(u16x8*)(out + (size_t)slot * 16384 + ((size_t)(ot * 4 + kk) * 64 + l) * 8) = u;
    } else {
        // compose: Wqe=Wq*We (slot2), Wkd=Wk*Wd (slot3), Wvd=Wv*Wd (slot4)
        const int cid = bid - 24;            // 0..191
        const int mat = cid >> 6;            // 0..2
        const int o = ((cid & 63) << 1) | (t >> 7);
        const int c = t & 127;
        const float* A = (mat == 0) ? Wq : (mat == 1) ? Wk : Wv;
        const float* B = (mat == 0) ? We : Wd;
        const float* bvec = (mat == 0) ? be : bd;
        float acc = 0.f;
        for (int m = 0; m < CC; ++m) acc += A[o * CC + m] * B[m * CC + c];
        const int ot = o >> 4, l15o = o & 15;
        const int kk = c >> 5, gc = (c >> 3) & 3, j = c & 7;
        const int l = gc * 16 + l15o;
        out[(size_t)(2 + mat) * 16384 + ((size_t)(ot * 4 + kk) * 64 + l) * 8 + j] = f2b(acc);
        if (c == 0) {
            float bacc = 0.f;
            for (int m = 0; m < CC; ++m) bacc += A[o * CC + m] * bvec[m];
            cvec[mat * CC + o] = bacc;
        }
    }
}

// ---------- kernel 1: front — 32-n tiles, 2 e-waves + 2 kv-waves ----------
__global__ __launch_bounds__(256) void k_front(
    const float* __restrict__ edge, const float* __restrict__ dvs,
    const u16* __restrict__ WeB, const u16* __restrict__ WdB,
    const u16* __restrict__ WqeB, const u16* __restrict__ WkdB,
    const u16* __restrict__ WvdB,
    const float* __restrict__ be, const float* __restrict__ bd,
    const float* __restrict__ bq,
    const float* __restrict__ cq, const float* __restrict__ ck,
    const float* __restrict__ cv,
    float* __restrict__ l2e_out,
    u16* __restrict__ qT, u16* __restrict__ kT, u16* __restrict__ vN)
{
    __shared__ u16 lds[2 * 32 * CP];   // bufA | bufB ; reused as bufT[128][40]
    u16* bufA = lds;
    u16* bufB = lds + 32 * CP;
    const int t = threadIdx.x;
    const int bt = blockIdx.y;
    const int n0b = blockIdx.x * 32;
    const float* eb = edge + (size_t)bt * CC * NN + n0b;
    const float* db = dvs + (size_t)bt * CC * NN + n0b;

    // stage: transpose [c][n] fp32 -> [n][c] bf16  (32 n x 128 c)
    {
        const int c4 = t >> 3, p = t & 7;
        float4 e[4], d[4];
#pragma unroll
        for (int m = 0; m < 4; ++m) {
            e[m] = *(const float4*)(eb + (size_t)(4 * c4 + m) * NN + 4 * p);
            d[m] = *(const float4*)(db + (size_t)(4 * c4 + m) * NN + 4 * p);
        }
#pragma unroll
        for (int n = 0; n < 4; ++n) {
            u16x4 ue, ud;
            ue[0] = f2b(((const float*)&e[0])[n]); ud[0] = f2b(((const float*)&d[0])[n]);
            ue[1] = f2b(((const float*)&e[1])[n]); ud[1] = f2b(((const float*)&d[1])[n]);
            ue[2] = f2b(((const float*)&e[2])[n]); ud[2] = f2b(((const float*)&d[2])[n]);
            ue[3] = f2b(((const float*)&e[3])[n]); ud[3] = f2b(((const float*)&d[3])[n]);
            *(u16x4*)&bufA[(4 * p + n) * CP + 4 * c4] = ue;
            *(u16x4*)&bufB[(4 * p + n) * CP + 4 * c4] = ud;
        }
    }
    __syncthreads();

    const int w = t >> 6, l = t & 63;
    const int l15 = l & 15, g = l >> 4;
    const bool is_e = (w < 2);
    const int nloc = (w & 1) * 16 + l15;
    const size_t gn = (size_t)bt * NN + n0b + nloc;

    bf16x8 bfrE[4], bfrD[4];
    if (is_e) loadB(bufA + nloc * CP, g, bfrE);
    loadB(bufB + nloc * CP, g, bfrD);
    __syncthreads();   // all LDS frag reads done -> lds reusable as bufT

    u16* bufT = lds;   // [128][40] u16

    if (is_e) {
        // --- ef/df accumulators (stats only) ---
        f32x4 aE[8], aD[8];
#pragma unroll
        for (int ot = 0; ot < 8; ++ot) {
            aE[ot] = *(const f32x4*)(be + 16 * ot + 4 * g);
            aD[ot] = *(const f32x4*)(bd + 16 * ot + 4 * g);
        }
#pragma unroll
        for (int ot = 0; ot < 8; ++ot)
#pragma unroll
            for (int kk = 0; kk < 4; ++kk) {
                aE[ot] = __builtin_amdgcn_mfma_f32_16x16x32_bf16(ldA(WeB, ot, kk, l), bfrE[kk], aE[ot], 0, 0, 0);
                aD[ot] = __builtin_amdgcn_mfma_f32_16x16x32_bf16(ldA(WdB, ot, kk, l), bfrD[kk], aD[ot], 0, 0, 0);
            }
        float s2e = 0.f, s2d = 0.f, sed = 0.f;
#pragma unroll
        for (int ot = 0; ot < 8; ++ot)
#pragma unroll
            for (int r = 0; r < 4; ++r) {
                const float fe = aE[ot][r], fd = aD[ot][r];
                s2e += fe * fe; s2d += fd * fd; sed += fe * fd;
            }
        s2e += __shfl_xor(s2e, 16); s2e += __shfl_xor(s2e, 32);
        s2d += __shfl_xor(s2d, 16); s2d += __shfl_xor(s2d, 32);
        sed += __shfl_xor(sed, 16); sed += __shfl_xor(sed, 32);
        const float le = sqrtf(s2e), ld = sqrtf(s2d);
        const float sim = (sed / ((le + 1e-6f) * (ld + 1e-6f)) + 1.0f) * 0.5f;
        if (g == 0) l2e_out[gn] = le;

        // --- q = sim*(Wqe*e + cq) + bq ---
        f32x4 aQ[8];
#pragma unroll
        for (int ot = 0; ot < 8; ++ot) aQ[ot] = *(const f32x4*)(cq + 16 * ot + 4 * g);
#pragma unroll
        for (int ot = 0; ot < 8; ++ot)
#pragma unroll
            for (int kk = 0; kk < 4; ++kk)
                aQ[ot] = __builtin_amdgcn_mfma_f32_16x16x32_bf16(ldA(WqeB, ot, kk, l), bfrE[kk], aQ[ot], 0, 0, 0);
#pragma unroll
        for (int ot = 0; ot < 8; ++ot) {
            f32x4 b4 = *(const f32x4*)(bq + 16 * ot + 4 * g);
            u16x4 u;
#pragma unroll
            for (int r = 0; r < 4; ++r) u[r] = f2b(sim * aQ[ot][r] + b4[r]);
            *(u16x4*)(qT + gn * CC + 16 * ot + 4 * g) = u;
        }
    } else {
        // --- kraw = Wkd*d + ck ---
        f32x4 aK[8];
#pragma unroll
        for (int ot = 0; ot < 8; ++ot) aK[ot] = *(const f32x4*)(ck + 16 * ot + 4 * g);
#pragma unroll
        for (int ot = 0; ot < 8; ++ot)
#pragma unroll
            for (int kk = 0; kk < 4; ++kk)
                aK[ot] = __builtin_amdgcn_mfma_f32_16x16x32_bf16(ldA(WkdB, ot, kk, l), bfrD[kk], aK[ot], 0, 0, 0);
#pragma unroll
        for (int ot = 0; ot < 8; ++ot) {
            u16x4 u;
#pragma unroll
            for (int r = 0; r < 4; ++r) u[r] = f2b(aK[ot][r]);
            *(u16x4*)(kT + gn * CC + 16 * ot + 4 * g) = u;
        }
        // --- vraw = Wvd*d + cv -> bufT (transpose to channel-major) ---
        f32x4 aV[8];
#pragma unroll
        for (int ot = 0; ot < 8; ++ot) aV[ot] = *(const f32x4*)(cv + 16 * ot + 4 * g);
#pragma unroll
        for (int ot = 0; ot < 8; ++ot)
#pragma unroll
            for (int kk = 0; kk < 4; ++kk)
                aV[ot] = __builtin_amdgcn_mfma_f32_16x16x32_bf16(ldA(WvdB, ot, kk, l), bfrD[kk], aV[ot], 0, 0, 0);
#pragma unroll
        for (int ot = 0; ot < 8; ++ot)
#pragma unroll
            for (int r = 0; r < 4; ++r)
                bufT[(16 * ot + 4 * g + r) * 40 + nloc] = f2b(aV[ot][r]);
    }
    __syncthreads();
    // coop coalesced vN store: [c][n]
#pragma unroll
    for (int p = 0; p < 2; ++p) {
        const int idx = t + 256 * p;
        const int c = idx >> 2, n8 = (idx & 3) * 8;
        *(u16x8*)(vN + ((size_t)bt * CC + c) * NN + n0b + n8) =
            *(const u16x8*)&bufT[c * 40 + n8];
    }
}

// ---------- kernel 2: spatial softmax of l2e -> density ----------
__global__ __launch_bounds__(256) void k_dens(const float* __restrict__ l2e,
                                              float* __restrict__ dens)
{
    __shared__ float red1[4];
    __shared__ float red2[4];
    const int bt = blockIdx.x, t = threadIdx.x;
    const int lane = t & 63, wid = t >> 6;
    const float* x = l2e + (size_t)bt * NN;
    float v[4], m = -1e30f;
#pragma unroll
    for (int i = 0; i < 4; ++i) { v[i] = x[t + 256 * i]; m = fmaxf(m, v[i]); }
#pragma unroll
    for (int off = 32; off >= 1; off >>= 1) m = fmaxf(m, __shfl_xor(m, off));
    if (lane == 0) red1[wid] = m;
    __syncthreads();
    m = fmaxf(fmaxf(red1[0], red1[1]), fmaxf(red1[2], red1[3]));
    float e[4], s = 0.f;
#pragma unroll
    for (int i = 0; i < 4; ++i) { e[i] = expf(v[i] - m); s += e[i]; }
#pragma unroll
    for (int off = 32; off >= 1; off >>= 1) s += __shfl_xor(s, off);
    if (lane == 0) red2[wid] = s;
    __syncthreads();
    s = red2[0] + red2[1] + red2[2] + red2[3];
    const float scale = 1024.0f / s;
#pragma unroll
    for (int i = 0; i < 4; ++i) dens[(size_t)bt * NN + t + 256 * i] = e[i] * scale;
}

// ---------- kernel 3: FUSED attention + conv + LIF, 8 waves (tt x qy-half) ----------
__global__ __launch_bounds__(512) void k_attnf(
    const u16* __restrict__ qT, const u16* __restrict__ kT,
    const u16* __restrict__ vN, const float* __restrict__ dens,
    const float* __restrict__ bk, const float* __restrict__ bv,
    const u16* __restrict__ WfB, const float* __restrict__ bf,
    float* __restrict__ out)
{
    __shared__ u16 lds_u16[26624];  // 53248 B
    const int t = threadIdx.x;
    const int id = blockIdx.x;
    const int b = id & 7, qx = id >> 3;   // XCD x owns b = x
    const int w = t >> 6, tt = w & 3, h = w >> 2;
    const int bt = b * 4 + tt;
    const int l = t & 63, l15 = l & 15, g = l >> 4;
    u16* att = lds_u16;                                   // [4][32][CPA]
    float* convq = (float*)(lds_u16 + 17408);             // [4][32][CQS] f32
    u16* P = lds_u16 + tt * 32 * PSTs;                    // overlays att region
    const size_t btNN = (size_t)bt * NN;
    const float invsq = 0.08838834764831843f;  // 1/sqrt(128)
    const int qyv = 16 * h + l15;              // this wave's qy rows

    // q fragments (only own qy half)
    u16x8 ql[4];
#pragma unroll
    for (int kk = 0; kk < 4; ++kk)
        ql[kk] = *(const u16x8*)(qT + (btNN + qx * 32 + qyv) * CC + 32 * kk + 8 * g);

    // qbk = q[qy]·bk
    float qbk = 0.f;
#pragma unroll
    for (int kk = 0; kk < 4; ++kk) {
        f32x4 b0 = *(const f32x4*)(bk + 32 * kk + 8 * g);
        f32x4 b1 = *(const f32x4*)(bk + 32 * kk + 8 * g + 4);
#pragma unroll
        for (int j = 0; j < 4; ++j) {
            qbk += b2f(ql[kk][j]) * b0[j];
            qbk += b2f(ql[kk][4 + j]) * b1[j];
        }
    }
    qbk += __shfl_xor(qbk, 16);
    qbk += __shfl_xor(qbk, 32);

    // ---- interleaved QK^T / P' / PV over 7 kx columns (no barriers) ----
    float ssum = 0.f;
    f32x4 o[8];
#pragma unroll
    for (int mt = 0; mt < 8; ++mt) o[mt] = (f32x4){0.f, 0.f, 0.f, 0.f};

#pragma unroll
    for (int i = 0; i < 7; ++i) {
        const int kxr = qx - 3 + i;
        const int kxc = min(max(kxr, 0), 31);
        const bool cval = (kxr == kxc);
        f32x4 acc[2];
#pragma unroll
        for (int mt = 0; mt < 2; ++mt) acc[mt] = (f32x4){0.f, 0.f, 0.f, 0.f};
#pragma unroll
        for (int kk = 0; kk < 4; ++kk)
#pragma unroll
            for (int mt = 0; mt < 2; ++mt) {
                bf16x8 ka = *(const bf16x8*)(kT + (btNN + kxc * 32 + 16 * mt + l15) * CC + 32 * kk + 8 * g);
                acc[mt] = __builtin_amdgcn_mfma_f32_16x16x32_bf16(
                    ka, __builtin_bit_cast(bf16x8, ql[kk]), acc[mt], 0, 0, 0);
            }
#pragma unroll
        for (int mt = 0; mt < 2; ++mt) {
            f32x4 d4 = *(const f32x4*)(dens + btNN + kxc * 32 + 16 * mt + 4 * g);
            u16x4 pw;
#pragma unroll
            for (int r = 0; r < 4; ++r) {
                const float s = (d4[r] * acc[mt][r] + qbk) * invsq;
                const int ky = 16 * mt + 4 * g + r;
                const int dy = ky - qyv;
                const bool vld = cval && (dy >= -3) && (dy <= 3);
                const float e = vld ? __expf(s) : 0.f;
                ssum += e;
                pw[r] = f2b(e * d4[r]);
            }
            *(u16x4*)&P[qyv * PSTs + 16 * mt + 4 * g] = pw;
        }
        // wave-private P rows: own-wave RAW only (rule 18 fence)
        asm volatile("s_waitcnt lgkmcnt(0)" ::: "memory");
        __builtin_amdgcn_sched_barrier(0);
        bf16x8 pb = *(const bf16x8*)&P[qyv * PSTs + 8 * g];
#pragma unroll
        for (int mt = 0; mt < 8; ++mt) {
            bf16x8 va = *(const bf16x8*)(vN + ((size_t)bt * CC + 16 * mt + l15) * NN + kxc * 32 + 8 * g);
            o[mt] = __builtin_amdgcn_mfma_f32_16x16x32_bf16(va, pb, o[mt], 0, 0, 0);
        }
    }
    float s = ssum;
    s += __shfl_xor(s, 16);
    s += __shfl_xor(s, 32);
    const float inv = 1.0f / s;

    __syncthreads();  // all P reads done before att overwrites the region

    // ---- O -> att_lds[tt][n][c] bf16 (inv scale + bv), own qy rows ----
    u16* attw = att + tt * 32 * CPA;
#pragma unroll
    for (int mt = 0; mt < 8; ++mt) {
        f32x4 bv4 = *(const f32x4*)(bv + 16 * mt + 4 * g);
        u16x4 ov;
#pragma unroll
        for (int r = 0; r < 4; ++r) ov[r] = f2b(o[mt][r] * inv + bv4[r]);
        *(u16x4*)&attw[qyv * CPA + 16 * mt + 4 * g] = ov;
    }
    __syncthreads();  // cross-wave: both qy halves of att ready

    // conv B-frags (need both halves)
    bf16x8 cb[4][2];
#pragma unroll
    for (int kk = 0; kk < 4; ++kk)
#pragma unroll
        for (int nt = 0; nt < 2; ++nt)
            cb[kk][nt] = *(const bf16x8*)&attw[(16 * nt + l15) * CPA + 32 * kk + 8 * g];

    // ---- conv + LIF in 4 c-quarters; wave h owns ot = 2*cr + h ----
    const int cl = t >> 4, n2 = (t & 15) * 2;  // LIF ownership (512 threads)
#pragma unroll
    for (int cr = 0; cr < 4; ++cr) {
        const int ot = 2 * cr + h;
        f32x4 ca[2];
#pragma unroll
        for (int nt = 0; nt < 2; ++nt) ca[nt] = *(const f32x4*)(bf + 16 * ot + 4 * g);
#pragma unroll
        for (int kk = 0; kk < 4; ++kk) {
            bf16x8 afr = ldA(WfB, ot, kk, l);
#pragma unroll
            for (int nt = 0; nt < 2; ++nt)
                ca[nt] = __builtin_amdgcn_mfma_f32_16x16x32_bf16(afr, cb[kk][nt], ca[nt], 0, 0, 0);
        }
#pragma unroll
        for (int nt = 0; nt < 2; ++nt)
#pragma unroll
            for (int r = 0; r < 4; ++r)
                convq[tt * 32 * CQS + (16 * h + 4 * g + r) * CQS + 16 * nt + l15] = ca[nt][r];
        __syncthreads();
        // LIF over tt for c = 32*cr + cl, n = qx*32 + n2, n2+1
        float m0 = 0.f, m1 = 0.f;
#pragma unroll
        for (int tt2 = 0; tt2 < 4; ++tt2) {
            float2 x = *(const float2*)&convq[tt2 * 32 * CQS + cl * CQS + n2];
            m0 = m0 * 0.5f + x.x;
            m1 = m1 * 0.5f + x.y;
            float2 sp;
            sp.x = (m0 > 1.0f) ? 1.0f : 0.0f; if (m0 > 1.0f) m0 = 0.f;
            sp.y = (m1 > 1.0f) ? 1.0f : 0.0f; if (m1 > 1.0f) m1 = 0.f;
            *(float2*)(out + ((size_t)(b * 4 + tt2) * CC + 32 * cr + cl) * NN + qx * 32 + n2) = sp;
        }
        __syncthreads();
    }
}

extern "C" void kernel_launch(void* const* d_in, const int* in_sizes, int n_in,
                              void* d_out, int out_size, void* d_ws, size_t ws_size,
                              hipStream_t stream) {
    (void)in_sizes; (void)n_in; (void)out_size; (void)ws_size;
    const float* edge = (const float*)d_in[0];
    const float* dvs  = (const float*)d_in[1];
    const float* We = (const float*)d_in[2];
    const float* be = (const float*)d_in[3];
    const float* Wd = (const float*)d_in[4];
    const float* bd = (const float*)d_in[5];
    const float* Wq = (const float*)d_in[6];
    const float* bq = (const float*)d_in[7];
    const float* Wk = (const float*)d_in[8];
    const float* bk = (const float*)d_in[9];
    const float* Wv = (const float*)d_in[10];
    const float* bv = (const float*)d_in[11];
    const float* Wf = (const float*)d_in[12];
    const float* bf = (const float*)d_in[13];
    float* out = (float*)d_out;

    const size_t S = (size_t)BTOT * NN * CC;  // 4.19M elems
    u16* qT   = (u16*)d_ws;
    u16* kT   = qT + S;
    u16* vN   = kT + S;
    u16* WbAll = vN + S;                      // 6 * 16384 u16
    float* fbase = (float*)(WbAll + 6 * 16384);
    float* cvec  = fbase;                     // 3 * 128
    float* l2e   = cvec + 3 * CC;
    float* dens  = l2e + BTOT * NN;
    u16* WeB  = WbAll + 0 * 16384;
    u16* WdB  = WbAll + 1 * 16384;
    u16* WqeB = WbAll + 2 * 16384;
    u16* WkdB = WbAll + 3 * 16384;
    u16* WvdB = WbAll + 4 * 16384;
    u16* WfB  = WbAll + 5 * 16384;
    float* cq = cvec;
    float* ck = cvec + CC;
    float* cv = cvec + 2 * CC;

    k_prep<<<216, 256, 0, stream>>>(We, Wd, Wf, Wq, Wk, Wv, be, bd, WbAll, cvec);
    k_front<<<dim3(32, BTOT), 256, 0, stream>>>(edge, dvs, WeB, WdB, WqeB, WkdB, WvdB,
                                                be, bd, bq, cq, ck, cv, l2e, qT, kT, vN);
    k_dens<<<BTOT, 256, 0, stream>>>(l2e, dens);
    k_attnf<<<256, 512, 0, stream>>>(qT, kT, vN, dens, bk, bv, WfB, bf, out);
}

// Round 9
// 67.968 us; speedup vs baseline: 1.1606x; 1.1606x over previous
//
#include <hip/hip_runtime.h>
#include <math.h>

#define CC 128   // channels
#define NN 1024  // H*W
#define BTOT 32  // B*T
#define CP 152   // k_front LDS row stride (bf16 elems)
#define PSTs 40  // P column-buffer row stride (u16): 80B
#define CPA 136  // att_lds row stride (u16): 272B = 17*16
#define CQS 36   // conv_q row stride (f32): 144B = 9*16

typedef unsigned short u16;
typedef u16 u16x8 __attribute__((ext_vector_type(8)));
typedef u16 u16x4 __attribute__((ext_vector_type(4)));
typedef __bf16 bf16x8 __attribute__((ext_vector_type(8)));
typedef float f32x4 __attribute__((ext_vector_type(4)));

__device__ __forceinline__ u16 f2b(float f) {
    unsigned int u = __float_as_uint(f);
    u += 0x7FFFu + ((u >> 16) & 1u);   // RNE
    return (u16)(u >> 16);
}
__device__ __forceinline__ float b2f(u16 u) {
    return __uint_as_float(((unsigned int)u) << 16);
}

// ---------- MFMA helpers ----------
// A-frag: lane l holds A[16*ot + (l&15)][32*kk + 8*(l>>4) + j], j=0..7.
// B-frag: lane l holds B[16*nt + (l&15)][32*kk + 8*(l>>4) + j].
// C/D: col = l&15 (B row), row = (l>>4)*4 + r (+16*ot) (A row).
__device__ __forceinline__ void loadB(const u16* brow, int g, bf16x8 bfr[4]) {
#pragma unroll
    for (int kk = 0; kk < 4; ++kk)
        bfr[kk] = *(const bf16x8*)(brow + kk * 32 + g * 8);
}
__device__ __forceinline__ bf16x8 ldA(const u16* __restrict__ WB, int ot, int kk, int l) {
    return *(const bf16x8*)(WB + ((size_t)(ot * 4 + kk) * 64 + l) * 8);
}

// ---------- kernel 0: prep — pack We/Wd/Wf AND compose+pack Wqe/Wkd/Wvd ----------
__global__ __launch_bounds__(256) void k_prep(
    const float* __restrict__ We, const float* __restrict__ Wd,
    const float* __restrict__ Wf, const float* __restrict__ Wq,
    const float* __restrict__ Wk, const float* __restrict__ Wv,
    const float* __restrict__ be, const float* __restrict__ bd,
    u16* __restrict__ out, float* __restrict__ cvec)
{
    const int bid = blockIdx.x, t = threadIdx.x;
    if (bid < 24) {
        // plain pack: We->slot0, Wd->slot1, Wf->slot5
        const int gid = bid * 256 + t;       // 0..6143
        const int wi = gid >> 11;            // 0..2
        const float* W = (wi == 0) ? We : (wi == 1) ? Wd : Wf;
        const int slot = (wi == 2) ? 5 : wi;
        const int rem = gid & 2047;
        const int ot = rem >> 8, kk = (rem >> 6) & 3, l = rem & 63;
        const int row = ot * 16 + (l & 15), col = kk * 32 + (l >> 4) * 8;
        float4 a = *(const float4*)(W + row * CC + col);
        float4 b = *(const float4*)(W + row * CC + col + 4);
        u16x8 u;
        u[0] = f2b(a.x); u[1] = f2b(a.y); u[2] = f2b(a.z); u[3] = f2b(a.w);
        u[4] = f2b(b.x); u[5] = f2b(b.y); u[6] = f2b(b.z); u[7] = f2b(b.w);
        *(u16x8*)(out + (size_t)slot * 16384 + ((size_t)(ot * 4 + kk) * 64 + l) * 8) = u;
    } else {
        // compose: Wqe=Wq*We (slot2), Wkd=Wk*Wd (slot3), Wvd=Wv*Wd (slot4)
        const int cid = bid - 24;            // 0..191
        const int mat = cid >> 6;            // 0..2
        const int o = ((cid & 63) << 1) | (t >> 7);
        const int c = t & 127;
        const float* A = (mat == 0) ? Wq : (mat == 1) ? Wk : Wv;
        const float* B = (mat == 0) ? We : Wd;
        const float* bvec = (mat == 0) ? be : bd;
        float acc = 0.f;
        for (int m = 0; m < CC; ++m) acc += A[o * CC + m] * B[m * CC + c];
        const int ot = o >> 4, l15o = o & 15;
        const int kk = c >> 5, gc = (c >> 3) & 3, j = c & 7;
        const int l = gc * 16 + l15o;
        out[(size_t)(2 + mat) * 16384 + ((size_t)(ot * 4 + kk) * 64 + l) * 8 + j] = f2b(acc);
        if (c == 0) {
            float bacc = 0.f;
            for (int m = 0; m < CC; ++m) bacc += A[o * CC + m] * bvec[m];
            cvec[mat * CC + o] = bacc;
        }
    }
}

// ---------- kernel 1: front — 64-n tiles, XCD-aligned grid ----------
// 1D grid of 512: bt = (id&7)*4 + ((id>>3)&3), tile = id>>5.
// Consecutive ids round-robin XCDs, so XCD x processes exactly b = x's 4 bt:
// its q/k/v writes (3.1 MB) stay in that XCD's L2 for k_attnf (b = id&7).
__global__ __launch_bounds__(256) void k_front(
    const float* __restrict__ edge, const float* __restrict__ dvs,
    const u16* __restrict__ WeB, const u16* __restrict__ WdB,
    const u16* __restrict__ WqeB, const u16* __restrict__ WkdB,
    const u16* __restrict__ WvdB,
    const float* __restrict__ be, const float* __restrict__ bd,
    const float* __restrict__ bq,
    const float* __restrict__ cq, const float* __restrict__ ck,
    const float* __restrict__ cv,
    float* __restrict__ l2e_out,
    u16* __restrict__ qT, u16* __restrict__ kT, u16* __restrict__ vN)
{
    __shared__ u16 bufA[64 * CP];
    __shared__ u16 bufB[64 * CP];
    const int t = threadIdx.x;
    const int id = blockIdx.x;
    const int bt = (id & 7) * 4 + ((id >> 3) & 3);
    const int n0b = (id >> 5) * 64;
    const float* eb = edge + (size_t)bt * CC * NN + n0b;
    const float* db = dvs + (size_t)bt * CC * NN + n0b;

    // stage: transpose [c][n] fp32 -> [n][c] bf16
#pragma unroll
    for (int j = 0; j < 2; ++j) {
        const int i = t + 256 * j;
        const int c4 = i >> 4, p = i & 15;
        float4 e[4], d[4];
#pragma unroll
        for (int m = 0; m < 4; ++m) {
            e[m] = *(const float4*)(eb + (size_t)(4 * c4 + m) * NN + 4 * p);
            d[m] = *(const float4*)(db + (size_t)(4 * c4 + m) * NN + 4 * p);
        }
#pragma unroll
        for (int n = 0; n < 4; ++n) {
            u16x4 ue, ud;
            ue[0] = f2b(((const float*)&e[0])[n]); ud[0] = f2b(((const float*)&d[0])[n]);
            ue[1] = f2b(((const float*)&e[1])[n]); ud[1] = f2b(((const float*)&d[1])[n]);
            ue[2] = f2b(((const float*)&e[2])[n]); ud[2] = f2b(((const float*)&d[2])[n]);
            ue[3] = f2b(((const float*)&e[3])[n]); ud[3] = f2b(((const float*)&d[3])[n]);
            *(u16x4*)&bufA[(4 * p + n) * CP + 4 * c4] = ue;
            *(u16x4*)&bufB[(4 * p + n) * CP + 4 * c4] = ud;
        }
    }
    __syncthreads();

    const int w = t >> 6, l = t & 63;
    const int l15 = l & 15, g = l >> 4;
    const int nloc = w * 16 + l15;
    const size_t gn = (size_t)bt * NN + n0b + nloc;

    bf16x8 bfrE[4], bfrD[4];
    loadB(bufA + nloc * CP, g, bfrE);
    loadB(bufB + nloc * CP, g, bfrD);

    // --- ef/df accumulators (stats only, never materialized) ---
    f32x4 aE[8], aD[8];
#pragma unroll
    for (int ot = 0; ot < 8; ++ot) {
        aE[ot] = *(const f32x4*)(be + 16 * ot + 4 * g);
        aD[ot] = *(const f32x4*)(bd + 16 * ot + 4 * g);
    }
#pragma unroll
    for (int ot = 0; ot < 8; ++ot)
#pragma unroll
        for (int kk = 0; kk < 4; ++kk) {
            aE[ot] = __builtin_amdgcn_mfma_f32_16x16x32_bf16(ldA(WeB, ot, kk, l), bfrE[kk], aE[ot], 0, 0, 0);
            aD[ot] = __builtin_amdgcn_mfma_f32_16x16x32_bf16(ldA(WdB, ot, kk, l), bfrD[kk], aD[ot], 0, 0, 0);
        }
    float s2e = 0.f, s2d = 0.f, sed = 0.f;
#pragma unroll
    for (int ot = 0; ot < 8; ++ot)
#pragma unroll
        for (int r = 0; r < 4; ++r) {
            const float fe = aE[ot][r], fd = aD[ot][r];
            s2e += fe * fe; s2d += fd * fd; sed += fe * fd;
        }
    s2e += __shfl_xor(s2e, 16); s2e += __shfl_xor(s2e, 32);
    s2d += __shfl_xor(s2d, 16); s2d += __shfl_xor(s2d, 32);
    sed += __shfl_xor(sed, 16); sed += __shfl_xor(sed, 32);
    const float le = sqrtf(s2e), ld = sqrtf(s2d);
    const float sim = (sed / ((le + 1e-6f) * (ld + 1e-6f)) + 1.0f) * 0.5f;
    if (g == 0) l2e_out[gn] = le;

    // --- q = sim*(Wqe*e + cq) + bq ---
    {
        f32x4 aQ[8];
#pragma unroll
        for (int ot = 0; ot < 8; ++ot) aQ[ot] = *(const f32x4*)(cq + 16 * ot + 4 * g);
#pragma unroll
        for (int ot = 0; ot < 8; ++ot)
#pragma unroll
            for (int kk = 0; kk < 4; ++kk)
                aQ[ot] = __builtin_amdgcn_mfma_f32_16x16x32_bf16(ldA(WqeB, ot, kk, l), bfrE[kk], aQ[ot], 0, 0, 0);
#pragma unroll
        for (int ot = 0; ot < 8; ++ot) {
            f32x4 b4 = *(const f32x4*)(bq + 16 * ot + 4 * g);
            u16x4 u;
#pragma unroll
            for (int r = 0; r < 4; ++r) u[r] = f2b(sim * aQ[ot][r] + b4[r]);
            *(u16x4*)(qT + gn * CC + 16 * ot + 4 * g) = u;
        }
    }
    // --- kraw = Wkd*d + ck ---
    {
        f32x4 aK[8];
#pragma unroll
        for (int ot = 0; ot < 8; ++ot) aK[ot] = *(const f32x4*)(ck + 16 * ot + 4 * g);
#pragma unroll
        for (int ot = 0; ot < 8; ++ot)
#pragma unroll
            for (int kk = 0; kk < 4; ++kk)
                aK[ot] = __builtin_amdgcn_mfma_f32_16x16x32_bf16(ldA(WkdB, ot, kk, l), bfrD[kk], aK[ot], 0, 0, 0);
#pragma unroll
        for (int ot = 0; ot < 8; ++ot) {
            u16x4 u;
#pragma unroll
            for (int r = 0; r < 4; ++r) u[r] = f2b(aK[ot][r]);
            *(u16x4*)(kT + gn * CC + 16 * ot + 4 * g) = u;
        }
    }
    // --- vraw = Wvd*d + cv ; channel-major vN[c][n] via LDS transpose ---
    {
        f32x4 aV[8];
#pragma unroll
        for (int ot = 0; ot < 8; ++ot) aV[ot] = *(const f32x4*)(cv + 16 * ot + 4 * g);
#pragma unroll
        for (int ot = 0; ot < 8; ++ot)
#pragma unroll
            for (int kk = 0; kk < 4; ++kk)
                aV[ot] = __builtin_amdgcn_mfma_f32_16x16x32_bf16(ldA(WvdB, ot, kk, l), bfrD[kk], aV[ot], 0, 0, 0);
        __syncthreads();  // bufA reads (loadB) all done -> safe to reuse
        u16* bufT = bufA; // [128][72] u16 = 9216 <= 64*CP
#pragma unroll
        for (int ot = 0; ot < 8; ++ot)
#pragma unroll
            for (int r = 0; r < 4; ++r)
                bufT[(16 * ot + 4 * g + r) * 72 + nloc] = f2b(aV[ot][r]);
        __syncthreads();
#pragma unroll
        for (int p = 0; p < 4; ++p) {
            const int idx = t + 256 * p;
            const int c = idx >> 3, n8 = (idx & 7) * 8;
            *(u16x8*)(vN + ((size_t)bt * CC + c) * NN + n0b + n8) =
                *(const u16x8*)&bufT[c * 72 + n8];
        }
    }
}

// ---------- kernel 2: spatial softmax of l2e -> density ----------
__global__ __launch_bounds__(256) void k_dens(const float* __restrict__ l2e,
                                              float* __restrict__ dens)
{
    __shared__ float red1[4];
    __shared__ float red2[4];
    const int bt = blockIdx.x, t = threadIdx.x;
    const int lane = t & 63, wid = t >> 6;
    const float* x = l2e + (size_t)bt * NN;
    float v[4], m = -1e30f;
#pragma unroll
    for (int i = 0; i < 4; ++i) { v[i] = x[t + 256 * i]; m = fmaxf(m, v[i]); }
#pragma unroll
    for (int off = 32; off >= 1; off >>= 1) m = fmaxf(m, __shfl_xor(m, off));
    if (lane == 0) red1[wid] = m;
    __syncthreads();
    m = fmaxf(fmaxf(red1[0], red1[1]), fmaxf(red1[2], red1[3]));
    float e[4], s = 0.f;
#pragma unroll
    for (int i = 0; i < 4; ++i) { e[i] = expf(v[i] - m); s += e[i]; }
#pragma unroll
    for (int off = 32; off >= 1; off >>= 1) s += __shfl_xor(s, off);
    if (lane == 0) red2[wid] = s;
    __syncthreads();
    s = red2[0] + red2[1] + red2[2] + red2[3];
    const float scale = 1024.0f / s;
#pragma unroll
    for (int i = 0; i < 4; ++i) dens[(size_t)bt * NN + t + 256 * i] = e[i] * scale;
}

// ---------- kernel 3: FUSED attention + output conv + LIF (R7 structure) ----------
// block = (b, qx); wave w = time step tt; bt = b*4+w.
__global__ __launch_bounds__(256) void k_attnf(
    const u16* __restrict__ qT, const u16* __restrict__ kT,
    const u16* __restrict__ vN, const float* __restrict__ dens,
    const float* __restrict__ bk, const float* __restrict__ bv,
    const u16* __restrict__ WfB, const float* __restrict__ bf,
    float* __restrict__ out)
{
    __shared__ u16 lds_u16[26624];  // 53248 B total
    const int t = threadIdx.x;
    const int id = blockIdx.x;
    const int b = id & 7, qx = id >> 3;   // XCD x owns b = x (matches k_front)
    const int w = t >> 6;
    const int bt = b * 4 + w;
    const int l = t & 63, l15 = l & 15, g = l >> 4;
    u16* att = lds_u16;                                   // [4][32][CPA]
    float* convq = (float*)(lds_u16 + 17408);             // [4][32][CQS] f32
    u16* P = lds_u16 + w * 32 * PSTs;                     // overlays att region
    const size_t btNN = (size_t)bt * NN;
    const float invsq = 0.08838834764831843f;  // 1/sqrt(128)

    // q fragments
    u16x8 ql[2][4];
#pragma unroll
    for (int nt = 0; nt < 2; ++nt)
#pragma unroll
        for (int kk = 0; kk < 4; ++kk)
            ql[nt][kk] = *(const u16x8*)(qT + (btNN + qx * 32 + 16 * nt + l15) * CC + 32 * kk + 8 * g);

    // qbk[nt] = q[qy]·bk
    float qbk[2] = {0.f, 0.f};
#pragma unroll
    for (int kk = 0; kk < 4; ++kk) {
        f32x4 b0 = *(const f32x4*)(bk + 32 * kk + 8 * g);
        f32x4 b1 = *(const f32x4*)(bk + 32 * kk + 8 * g + 4);
#pragma unroll
        for (int nt = 0; nt < 2; ++nt)
#pragma unroll
            for (int j = 0; j < 4; ++j) {
                qbk[nt] += b2f(ql[nt][kk][j]) * b0[j];
                qbk[nt] += b2f(ql[nt][kk][4 + j]) * b1[j];
            }
    }
#pragma unroll
    for (int nt = 0; nt < 2; ++nt) {
        qbk[nt] += __shfl_xor(qbk[nt], 16);
        qbk[nt] += __shfl_xor(qbk[nt], 32);
    }

    // ---- interleaved QK^T / P' / PV over the 7 kx columns ----
    float ssum[2] = {0.f, 0.f};
    f32x4 o[8][2];
#pragma unroll
    for (int mt = 0; mt < 8; ++mt)
#pragma unroll
        for (int nt = 0; nt < 2; ++nt) o[mt][nt] = (f32x4){0.f, 0.f, 0.f, 0.f};

#pragma unroll
    for (int i = 0; i < 7; ++i) {
        const int kxr = qx - 3 + i;
        const int kxc = min(max(kxr, 0), 31);
        const bool cval = (kxr == kxc);
        f32x4 acc[2][2];
#pragma unroll
        for (int mt = 0; mt < 2; ++mt)
#pragma unroll
            for (int nt = 0; nt < 2; ++nt) acc[mt][nt] = (f32x4){0.f, 0.f, 0.f, 0.f};
#pragma unroll
        for (int kk = 0; kk < 4; ++kk)
#pragma unroll
            for (int mt = 0; mt < 2; ++mt) {
                bf16x8 ka = *(const bf16x8*)(kT + (btNN + kxc * 32 + 16 * mt + l15) * CC + 32 * kk + 8 * g);
#pragma unroll
                for (int nt = 0; nt < 2; ++nt)
                    acc[mt][nt] = __builtin_amdgcn_mfma_f32_16x16x32_bf16(
                        ka, __builtin_bit_cast(bf16x8, ql[nt][kk]), acc[mt][nt], 0, 0, 0);
            }
#pragma unroll
        for (int mt = 0; mt < 2; ++mt) {
            f32x4 d4 = *(const f32x4*)(dens + btNN + kxc * 32 + 16 * mt + 4 * g);
#pragma unroll
            for (int nt = 0; nt < 2; ++nt) {
                const int qyv = l15 + 16 * nt;
                u16x4 pw;
#pragma unroll
                for (int r = 0; r < 4; ++r) {
                    const float s = (d4[r] * acc[mt][nt][r] + qbk[nt]) * invsq;
                    const int ky = 16 * mt + 4 * g + r;
                    const int dy = ky - qyv;
                    const bool vld = cval && (dy >= -3) && (dy <= 3);
                    const float e = vld ? __expf(s) : 0.f;
                    ssum[nt] += e;
                    pw[r] = f2b(e * d4[r]);
                }
                *(u16x4*)&P[qyv * PSTs + 16 * mt + 4 * g] = pw;
            }
        }
        asm volatile("s_waitcnt lgkmcnt(0)" ::: "memory");
        __builtin_amdgcn_sched_barrier(0);
        bf16x8 pb[2];
#pragma unroll
        for (int nt = 0; nt < 2; ++nt)
            pb[nt] = *(const bf16x8*)&P[(16 * nt + l15) * PSTs + 8 * g];
#pragma unroll
        for (int mt = 0; mt < 8; ++mt) {
            bf16x8 va = *(const bf16x8*)(vN + ((size_t)bt * CC + 16 * mt + l15) * NN + kxc * 32 + 8 * g);
#pragma unroll
            for (int nt = 0; nt < 2; ++nt)
                o[mt][nt] = __builtin_amdgcn_mfma_f32_16x16x32_bf16(va, pb[nt], o[mt][nt], 0, 0, 0);
        }
    }
    float inv[2];
#pragma unroll
    for (int nt = 0; nt < 2; ++nt) {
        float s = ssum[nt];
        s += __shfl_xor(s, 16);
        s += __shfl_xor(s, 32);
        inv[nt] = 1.0f / s;
    }

    __syncthreads();  // all P reads done before att overwrites the region

    // ---- O -> att_lds[w][n][c] bf16 (inv scale + bv) ----
    u16* attw = att + w * 32 * CPA;
#pragma unroll
    for (int mt = 0; mt < 8; ++mt) {
        f32x4 bv4 = *(const f32x4*)(bv + 16 * mt + 4 * g);
#pragma unroll
        for (int nt = 0; nt < 2; ++nt) {
            u16x4 ov;
#pragma unroll
            for (int r = 0; r < 4; ++r) ov[r] = f2b(o[mt][nt][r] * inv[nt] + bv4[r]);
            *(u16x4*)&attw[(16 * nt + l15) * CPA + 16 * mt + 4 * g] = ov;
        }
    }
    asm volatile("s_waitcnt lgkmcnt(0)" ::: "memory");
    __builtin_amdgcn_sched_barrier(0);

    // conv B-frags from own wave's att slice
    bf16x8 cb[4][2];
#pragma unroll
    for (int kk = 0; kk < 4; ++kk)
#pragma unroll
        for (int nt = 0; nt < 2; ++nt)
            cb[kk][nt] = *(const bf16x8*)&attw[(16 * nt + l15) * CPA + 32 * kk + 8 * g];

    // ---- conv + LIF in 4 c-quarters ----
    const int cl = t >> 3, n4 = (t & 7) * 4;  // LIF ownership
#pragma unroll
    for (int cr = 0; cr < 4; ++cr) {
#pragma unroll
        for (int oi = 0; oi < 2; ++oi) {
            const int ot = 2 * cr + oi;
            f32x4 ca[2];
#pragma unroll
            for (int nt = 0; nt < 2; ++nt) ca[nt] = *(const f32x4*)(bf + 16 * ot + 4 * g);
#pragma unroll
            for (int kk = 0; kk < 4; ++kk) {
                bf16x8 afr = ldA(WfB, ot, kk, l);
#pragma unroll
                for (int nt = 0; nt < 2; ++nt)
                    ca[nt] = __builtin_amdgcn_mfma_f32_16x16x32_bf16(afr, cb[kk][nt], ca[nt], 0, 0, 0);
            }
#pragma unroll
            for (int nt = 0; nt < 2; ++nt)
#pragma unroll
                for (int r = 0; r < 4; ++r)
                    convq[w * 32 * CQS + (16 * oi + 4 * g + r) * CQS + 16 * nt + l15] = ca[nt][r];
        }
        __syncthreads();
        // LIF over tt for c = 32*cr + cl, n = qx*32 + n4..n4+3
        f32x4 mem = {0.f, 0.f, 0.f, 0.f};
#pragma unroll
        for (int tt = 0; tt < 4; ++tt) {
            f32x4 x = *(const f32x4*)&convq[tt * 32 * CQS + cl * CQS + n4];
            f32x4 mv = mem * 0.5f + x;
            float4 sp;
            sp.x = (mv[0] > 1.0f) ? 1.0f : 0.0f; if (mv[0] > 1.0f) mv[0] = 0.f;
            sp.y = (mv[1] > 1.0f) ? 1.0f : 0.0f; if (mv[1] > 1.0f) mv[1] = 0.f;
            sp.z = (mv[2] > 1.0f) ? 1.0f : 0.0f; if (mv[2] > 1.0f) mv[2] = 0.f;
            sp.w = (mv[3] > 1.0f) ? 1.0f : 0.0f; if (mv[3] > 1.0f) mv[3] = 0.f;
            *(float4*)(out + ((size_t)(b * 4 + tt) * CC + 32 * cr + cl) * NN + qx * 32 + n4) = sp;
            mem = mv;
        }
        __syncthreads();
    }
}

extern "C" void kernel_launch(void* const* d_in, const int* in_sizes, int n_in,
                              void* d_out, int out_size, void* d_ws, size_t ws_size,
                              hipStream_t stream) {
    (void)in_sizes; (void)n_in; (void)out_size; (void)ws_size;
    const float* edge = (const float*)d_in[0];
    const float* dvs  = (const float*)d_in[1];
    const float* We = (const float*)d_in[2];
    const float* be = (const float*)d_in[3];
    const float* Wd = (const float*)d_in[4];
    const float* bd = (const float*)d_in[5];
    const float* Wq = (const float*)d_in[6];
    const float* bq = (const float*)d_in[7];
    const float* Wk = (const float*)d_in[8];
    const float* bk = (const float*)d_in[9];
    const float* Wv = (const float*)d_in[10];
    const float* bv = (const float*)d_in[11];
    const float* Wf = (const float*)d_in[12];
    const float* bf = (const float*)d_in[13];
    float* out = (float*)d_out;

    const size_t S = (size_t)BTOT * NN * CC;  // 4.19M elems
    u16* qT   = (u16*)d_ws;
    u16* kT   = qT + S;
    u16* vN   = kT + S;
    u16* WbAll = vN + S;                      // 6 * 16384 u16
    float* fbase = (float*)(WbAll + 6 * 16384);
    float* cvec  = fbase;                     // 3 * 128
    float* l2e   = cvec + 3 * CC;
    float* dens  = l2e + BTOT * NN;
    u16* WeB  = WbAll + 0 * 16384;
    u16* WdB  = WbAll + 1 * 16384;
    u16* WqeB = WbAll + 2 * 16384;
    u16* WkdB = WbAll + 3 * 16384;
    u16* WvdB = WbAll + 4 * 16384;
    u16* WfB  = WbAll + 5 * 16384;
    float* cq = cvec;
    float* ck = cvec + CC;
    float* cv = cvec + 2 * CC;

    k_prep<<<216, 256, 0, stream>>>(We, Wd, Wf, Wq, Wk, Wv, be, bd, WbAll, cvec);
    k_front<<<512, 256, 0, stream>>>(edge, dvs, WeB, WdB, WqeB, WkdB, WvdB,
                                     be, bd, bq, cq, ck, cv, l2e, qT, kT, vN);
    k_dens<<<BTOT, 256, 0, stream>>>(l2e, dens);
    k_attnf<<<256, 256, 0, stream>>>(qT, kT, vN, dens, bk, bv, WfB, bf, out);
}

// Round 10
// 64.993 us; speedup vs baseline: 1.2138x; 1.0458x over previous
//
#include <hip/hip_runtime.h>
#include <math.h>

#define CC 128   // channels
#define NN 1024  // H*W
#define BTOT 32  // B*T
#define CP 152   // k_front LDS row stride (bf16 elems)
#define PSTs 40  // P column-buffer row stride (u16): 80B
#define CPA 136  // att_lds row stride (u16): 272B = 17*16
#define CQS 36   // conv_q row stride (f32): 144B = 9*16

typedef unsigned short u16;
typedef u16 u16x8 __attribute__((ext_vector_type(8)));
typedef u16 u16x4 __attribute__((ext_vector_type(4)));
typedef __bf16 bf16x8 __attribute__((ext_vector_type(8)));
typedef float f32x4 __attribute__((ext_vector_type(4)));

__device__ __forceinline__ u16 f2b(float f) {
    unsigned int u = __float_as_uint(f);
    u += 0x7FFFu + ((u >> 16) & 1u);   // RNE
    return (u16)(u >> 16);
}
__device__ __forceinline__ float b2f(u16 u) {
    return __uint_as_float(((unsigned int)u) << 16);
}

// ---------- MFMA helpers ----------
// A-frag: lane l holds A[16*ot + (l&15)][32*kk + 8*(l>>4) + j], j=0..7.
// B-frag: lane l holds B[16*nt + (l&15)][32*kk + 8*(l>>4) + j].
// C/D: col = l&15 (B row), row = (l>>4)*4 + r (+16*ot) (A row).
__device__ __forceinline__ void loadB(const u16* brow, int g, bf16x8 bfr[4]) {
#pragma unroll
    for (int kk = 0; kk < 4; ++kk)
        bfr[kk] = *(const bf16x8*)(brow + kk * 32 + g * 8);
}
__device__ __forceinline__ bf16x8 ldA(const u16* __restrict__ WB, int ot, int kk, int l) {
    return *(const bf16x8*)(WB + ((size_t)(ot * 4 + kk) * 64 + l) * 8);
}

// ---------- kernel 0: prep — pack We/Wd/Wf AND compose+pack Wqe/Wkd/Wvd ----------
__global__ __launch_bounds__(256) void k_prep(
    const float* __restrict__ We, const float* __restrict__ Wd,
    const float* __restrict__ Wf, const float* __restrict__ Wq,
    const float* __restrict__ Wk, const float* __restrict__ Wv,
    const float* __restrict__ be, const float* __restrict__ bd,
    u16* __restrict__ out, float* __restrict__ cvec)
{
    const int bid = blockIdx.x, t = threadIdx.x;
    if (bid < 24) {
        // plain pack: We->slot0, Wd->slot1, Wf->slot5
        const int gid = bid * 256 + t;       // 0..6143
        const int wi = gid >> 11;            // 0..2
        const float* W = (wi == 0) ? We : (wi == 1) ? Wd : Wf;
        const int slot = (wi == 2) ? 5 : wi;
        const int rem = gid & 2047;
        const int ot = rem >> 8, kk = (rem >> 6) & 3, l = rem & 63;
        const int row = ot * 16 + (l & 15), col = kk * 32 + (l >> 4) * 8;
        float4 a = *(const float4*)(W + row * CC + col);
        float4 b = *(const float4*)(W + row * CC + col + 4);
        u16x8 u;
        u[0] = f2b(a.x); u[1] = f2b(a.y); u[2] = f2b(a.z); u[3] = f2b(a.w);
        u[4] = f2b(b.x); u[5] = f2b(b.y); u[6] = f2b(b.z); u[7] = f2b(b.w);
        *(u16x8*)(out + (size_t)slot * 16384 + ((size_t)(ot * 4 + kk) * 64 + l) * 8) = u;
    } else {
        // compose: Wqe=Wq*We (slot2), Wkd=Wk*Wd (slot3), Wvd=Wv*Wd (slot4)
        const int cid = bid - 24;            // 0..191
        const int mat = cid >> 6;            // 0..2
        const int o = ((cid & 63) << 1) | (t >> 7);
        const int c = t & 127;
        const float* A = (mat == 0) ? Wq : (mat == 1) ? Wk : Wv;
        const float* B = (mat == 0) ? We : Wd;
        const float* bvec = (mat == 0) ? be : bd;
        float acc = 0.f;
        for (int m = 0; m < CC; ++m) acc += A[o * CC + m] * B[m * CC + c];
        const int ot = o >> 4, l15o = o & 15;
        const int kk = c >> 5, gc = (c >> 3) & 3, j = c & 7;
        const int l = gc * 16 + l15o;
        out[(size_t)(2 + mat) * 16384 + ((size_t)(ot * 4 + kk) * 64 + l) * 8 + j] = f2b(acc);
        if (c == 0) {
            float bacc = 0.f;
            for (int m = 0; m < CC; ++m) bacc += A[o * CC + m] * bvec[m];
            cvec[mat * CC + o] = bacc;
        }
    }
}

// ---------- kernel 1: front — 64-n tiles, XCD-aligned grid ----------
// 1D grid of 512: bt = (id&7)*4 + ((id>>3)&3), tile = id>>5.
// Also emits eexp = exp(l2e) per n and per-block partial sums of eexp
// (deterministic shfl-tree), replacing the separate k_dens kernel.
__global__ __launch_bounds__(256) void k_front(
    const float* __restrict__ edge, const float* __restrict__ dvs,
    const u16* __restrict__ WeB, const u16* __restrict__ WdB,
    const u16* __restrict__ WqeB, const u16* __restrict__ WkdB,
    const u16* __restrict__ WvdB,
    const float* __restrict__ be, const float* __restrict__ bd,
    const float* __restrict__ bq,
    const float* __restrict__ cq, const float* __restrict__ ck,
    const float* __restrict__ cv,
    float* __restrict__ eexp_out, float* __restrict__ partial,
    u16* __restrict__ qT, u16* __restrict__ kT, u16* __restrict__ vN)
{
    __shared__ u16 bufA[64 * CP];
    __shared__ u16 bufB[64 * CP];
    __shared__ float redp[4];
    const int t = threadIdx.x;
    const int id = blockIdx.x;
    const int bt = (id & 7) * 4 + ((id >> 3) & 3);
    const int n0b = (id >> 5) * 64;
    const float* eb = edge + (size_t)bt * CC * NN + n0b;
    const float* db = dvs + (size_t)bt * CC * NN + n0b;

    // stage: transpose [c][n] fp32 -> [n][c] bf16
#pragma unroll
    for (int j = 0; j < 2; ++j) {
        const int i = t + 256 * j;
        const int c4 = i >> 4, p = i & 15;
        float4 e[4], d[4];
#pragma unroll
        for (int m = 0; m < 4; ++m) {
            e[m] = *(const float4*)(eb + (size_t)(4 * c4 + m) * NN + 4 * p);
            d[m] = *(const float4*)(db + (size_t)(4 * c4 + m) * NN + 4 * p);
        }
#pragma unroll
        for (int n = 0; n < 4; ++n) {
            u16x4 ue, ud;
            ue[0] = f2b(((const float*)&e[0])[n]); ud[0] = f2b(((const float*)&d[0])[n]);
            ue[1] = f2b(((const float*)&e[1])[n]); ud[1] = f2b(((const float*)&d[1])[n]);
            ue[2] = f2b(((const float*)&e[2])[n]); ud[2] = f2b(((const float*)&d[2])[n]);
            ue[3] = f2b(((const float*)&e[3])[n]); ud[3] = f2b(((const float*)&d[3])[n]);
            *(u16x4*)&bufA[(4 * p + n) * CP + 4 * c4] = ue;
            *(u16x4*)&bufB[(4 * p + n) * CP + 4 * c4] = ud;
        }
    }
    __syncthreads();

    const int w = t >> 6, l = t & 63;
    const int l15 = l & 15, g = l >> 4;
    const int nloc = w * 16 + l15;
    const size_t gn = (size_t)bt * NN + n0b + nloc;

    bf16x8 bfrE[4], bfrD[4];
    loadB(bufA + nloc * CP, g, bfrE);
    loadB(bufB + nloc * CP, g, bfrD);

    // --- ef/df accumulators (stats only, never materialized) ---
    f32x4 aE[8], aD[8];
#pragma unroll
    for (int ot = 0; ot < 8; ++ot) {
        aE[ot] = *(const f32x4*)(be + 16 * ot + 4 * g);
        aD[ot] = *(const f32x4*)(bd + 16 * ot + 4 * g);
    }
#pragma unroll
    for (int ot = 0; ot < 8; ++ot)
#pragma unroll
        for (int kk = 0; kk < 4; ++kk) {
            aE[ot] = __builtin_amdgcn_mfma_f32_16x16x32_bf16(ldA(WeB, ot, kk, l), bfrE[kk], aE[ot], 0, 0, 0);
            aD[ot] = __builtin_amdgcn_mfma_f32_16x16x32_bf16(ldA(WdB, ot, kk, l), bfrD[kk], aD[ot], 0, 0, 0);
        }
    float s2e = 0.f, s2d = 0.f, sed = 0.f;
#pragma unroll
    for (int ot = 0; ot < 8; ++ot)
#pragma unroll
        for (int r = 0; r < 4; ++r) {
            const float fe = aE[ot][r], fd = aD[ot][r];
            s2e += fe * fe; s2d += fd * fd; sed += fe * fd;
        }
    s2e += __shfl_xor(s2e, 16); s2e += __shfl_xor(s2e, 32);
    s2d += __shfl_xor(s2d, 16); s2d += __shfl_xor(s2d, 32);
    sed += __shfl_xor(sed, 16); sed += __shfl_xor(sed, 32);
    const float le = sqrtf(s2e), ld = sqrtf(s2d);
    const float sim = (sed / ((le + 1e-6f) * (ld + 1e-6f)) + 1.0f) * 0.5f;
    // eexp = exp(l2e) (no max-shift: le <= ~35 so e^le well within fp32)
    const float ee = __expf(le);
    if (g == 0) eexp_out[gn] = ee;
    // wave partial sum over 16 distinct n (xor 1,2,4,8 stays within g-group;
    // each group holds identical values, so result = sum over l15)
    {
        float s = ee;
        s += __shfl_xor(s, 1); s += __shfl_xor(s, 2);
        s += __shfl_xor(s, 4); s += __shfl_xor(s, 8);
        if (l == 0) redp[w] = s;
    }

    // --- q = sim*(Wqe*e + cq) + bq ---
    {
        f32x4 aQ[8];
#pragma unroll
        for (int ot = 0; ot < 8; ++ot) aQ[ot] = *(const f32x4*)(cq + 16 * ot + 4 * g);
#pragma unroll
        for (int ot = 0; ot < 8; ++ot)
#pragma unroll
            for (int kk = 0; kk < 4; ++kk)
                aQ[ot] = __builtin_amdgcn_mfma_f32_16x16x32_bf16(ldA(WqeB, ot, kk, l), bfrE[kk], aQ[ot], 0, 0, 0);
#pragma unroll
        for (int ot = 0; ot < 8; ++ot) {
            f32x4 b4 = *(const f32x4*)(bq + 16 * ot + 4 * g);
            u16x4 u;
#pragma unroll
            for (int r = 0; r < 4; ++r) u[r] = f2b(sim * aQ[ot][r] + b4[r]);
            *(u16x4*)(qT + gn * CC + 16 * ot + 4 * g) = u;
        }
    }
    // --- kraw = Wkd*d + ck ---
    {
        f32x4 aK[8];
#pragma unroll
        for (int ot = 0; ot < 8; ++ot) aK[ot] = *(const f32x4*)(ck + 16 * ot + 4 * g);
#pragma unroll
        for (int ot = 0; ot < 8; ++ot)
#pragma unroll
            for (int kk = 0; kk < 4; ++kk)
                aK[ot] = __builtin_amdgcn_mfma_f32_16x16x32_bf16(ldA(WkdB, ot, kk, l), bfrD[kk], aK[ot], 0, 0, 0);
#pragma unroll
        for (int ot = 0; ot < 8; ++ot) {
            u16x4 u;
#pragma unroll
            for (int r = 0; r < 4; ++r) u[r] = f2b(aK[ot][r]);
            *(u16x4*)(kT + gn * CC + 16 * ot + 4 * g) = u;
        }
    }
    // --- vraw = Wvd*d + cv ; channel-major vN[c][n] via LDS transpose ---
    {
        f32x4 aV[8];
#pragma unroll
        for (int ot = 0; ot < 8; ++ot) aV[ot] = *(const f32x4*)(cv + 16 * ot + 4 * g);
#pragma unroll
        for (int ot = 0; ot < 8; ++ot)
#pragma unroll
            for (int kk = 0; kk < 4; ++kk)
                aV[ot] = __builtin_amdgcn_mfma_f32_16x16x32_bf16(ldA(WvdB, ot, kk, l), bfrD[kk], aV[ot], 0, 0, 0);
        __syncthreads();  // bufA reads (loadB) all done; redp written
        if (t == 0)
            partial[(size_t)bt * 16 + (id >> 5)] = redp[0] + redp[1] + redp[2] + redp[3];
        u16* bufT = bufA; // [128][72] u16 = 9216 <= 64*CP
#pragma unroll
        for (int ot = 0; ot < 8; ++ot)
#pragma unroll
            for (int r = 0; r < 4; ++r)
                bufT[(16 * ot + 4 * g + r) * 72 + nloc] = f2b(aV[ot][r]);
        __syncthreads();
#pragma unroll
        for (int p = 0; p < 4; ++p) {
            const int idx = t + 256 * p;
            const int c = idx >> 3, n8 = (idx & 7) * 8;
            *(u16x8*)(vN + ((size_t)bt * CC + c) * NN + n0b + n8) =
                *(const u16x8*)&bufT[c * 72 + n8];
        }
    }
}

// ---------- kernel 2: FUSED attention + output conv + LIF ----------
// block = (b, qx); wave w = time step tt; bt = b*4+w.
// dens computed on the fly: dens[n] = (1024/S) * eexp[n], S = sum of 16 partials.
__global__ __launch_bounds__(256) void k_attnf(
    const u16* __restrict__ qT, const u16* __restrict__ kT,
    const u16* __restrict__ vN, const float* __restrict__ eexp,
    const float* __restrict__ partial,
    const float* __restrict__ bk, const float* __restrict__ bv,
    const u16* __restrict__ WfB, const float* __restrict__ bf,
    float* __restrict__ out)
{
    __shared__ u16 lds_u16[26624];  // 53248 B total
    const int t = threadIdx.x;
    const int id = blockIdx.x;
    const int b = id & 7, qx = id >> 3;   // XCD x owns b = x (matches k_front)
    const int w = t >> 6;
    const int bt = b * 4 + w;
    const int l = t & 63, l15 = l & 15, g = l >> 4;
    u16* att = lds_u16;                                   // [4][32][CPA]
    float* convq = (float*)(lds_u16 + 17408);             // [4][32][CQS] f32
    u16* P = lds_u16 + w * 32 * PSTs;                     // overlays att region
    const size_t btNN = (size_t)bt * NN;
    const float invsq = 0.08838834764831843f;  // 1/sqrt(128)

    // softmax denom for this bt (fixed order -> deterministic)
    float S = 0.f;
    {
        const float* pp = partial + (size_t)bt * 16;
#pragma unroll
        for (int i = 0; i < 16; ++i) S += pp[i];
    }
    const float dscale = 1024.0f / S;

    // q fragments
    u16x8 ql[2][4];
#pragma unroll
    for (int nt = 0; nt < 2; ++nt)
#pragma unroll
        for (int kk = 0; kk < 4; ++kk)
            ql[nt][kk] = *(const u16x8*)(qT + (btNN + qx * 32 + 16 * nt + l15) * CC + 32 * kk + 8 * g);

    // qbk[nt] = q[qy]·bk
    float qbk[2] = {0.f, 0.f};
#pragma unroll
    for (int kk = 0; kk < 4; ++kk) {
        f32x4 b0 = *(const f32x4*)(bk + 32 * kk + 8 * g);
        f32x4 b1 = *(const f32x4*)(bk + 32 * kk + 8 * g + 4);
#pragma unroll
        for (int nt = 0; nt < 2; ++nt)
#pragma unroll
            for (int j = 0; j < 4; ++j) {
                qbk[nt] += b2f(ql[nt][kk][j]) * b0[j];
                qbk[nt] += b2f(ql[nt][kk][4 + j]) * b1[j];
            }
    }
#pragma unroll
    for (int nt = 0; nt < 2; ++nt) {
        qbk[nt] += __shfl_xor(qbk[nt], 16);
        qbk[nt] += __shfl_xor(qbk[nt], 32);
    }

    // ---- interleaved QK^T / P' / PV over the 7 kx columns ----
    float ssum[2] = {0.f, 0.f};
    f32x4 o[8][2];
#pragma unroll
    for (int mt = 0; mt < 8; ++mt)
#pragma unroll
        for (int nt = 0; nt < 2; ++nt) o[mt][nt] = (f32x4){0.f, 0.f, 0.f, 0.f};

#pragma unroll
    for (int i = 0; i < 7; ++i) {
        const int kxr = qx - 3 + i;
        const int kxc = min(max(kxr, 0), 31);
        const bool cval = (kxr == kxc);
        f32x4 acc[2][2];
#pragma unroll
        for (int mt = 0; mt < 2; ++mt)
#pragma unroll
            for (int nt = 0; nt < 2; ++nt) acc[mt][nt] = (f32x4){0.f, 0.f, 0.f, 0.f};
#pragma unroll
        for (int kk = 0; kk < 4; ++kk)
#pragma unroll
            for (int mt = 0; mt < 2; ++mt) {
                bf16x8 ka = *(const bf16x8*)(kT + (btNN + kxc * 32 + 16 * mt + l15) * CC + 32 * kk + 8 * g);
#pragma unroll
                for (int nt = 0; nt < 2; ++nt)
                    acc[mt][nt] = __builtin_amdgcn_mfma_f32_16x16x32_bf16(
                        ka, __builtin_bit_cast(bf16x8, ql[nt][kk]), acc[mt][nt], 0, 0, 0);
            }
#pragma unroll
        for (int mt = 0; mt < 2; ++mt) {
            f32x4 ee4 = *(const f32x4*)(eexp + btNN + kxc * 32 + 16 * mt + 4 * g);
            f32x4 d4;
#pragma unroll
            for (int r = 0; r < 4; ++r) d4[r] = dscale * ee4[r];
#pragma unroll
            for (int nt = 0; nt < 2; ++nt) {
                const int qyv = l15 + 16 * nt;
                u16x4 pw;
#pragma unroll
                for (int r = 0; r < 4; ++r) {
                    const float s = (d4[r] * acc[mt][nt][r] + qbk[nt]) * invsq;
                    const int ky = 16 * mt + 4 * g + r;
                    const int dy = ky - qyv;
                    const bool vld = cval && (dy >= -3) && (dy <= 3);
                    const float e = vld ? __expf(s) : 0.f;
                    ssum[nt] += e;
                    pw[r] = f2b(e * d4[r]);
                }
                *(u16x4*)&P[qyv * PSTs + 16 * mt + 4 * g] = pw;
            }
        }
        asm volatile("s_waitcnt lgkmcnt(0)" ::: "memory");
        __builtin_amdgcn_sched_barrier(0);
        bf16x8 pb[2];
#pragma unroll
        for (int nt = 0; nt < 2; ++nt)
            pb[nt] = *(const bf16x8*)&P[(16 * nt + l15) * PSTs + 8 * g];
#pragma unroll
        for (int mt = 0; mt < 8; ++mt) {
            bf16x8 va = *(const bf16x8*)(vN + ((size_t)bt * CC + 16 * mt + l15) * NN + kxc * 32 + 8 * g);
#pragma unroll
            for (int nt = 0; nt < 2; ++nt)
                o[mt][nt] = __builtin_amdgcn_mfma_f32_16x16x32_bf16(va, pb[nt], o[mt][nt], 0, 0, 0);
        }
    }
    float inv[2];
#pragma unroll
    for (int nt = 0; nt < 2; ++nt) {
        float s = ssum[nt];
        s += __shfl_xor(s, 16);
        s += __shfl_xor(s, 32);
        inv[nt] = 1.0f / s;
    }

    __syncthreads();  // all P reads done before att overwrites the region

    // ---- O -> att_lds[w][n][c] bf16 (inv scale + bv) ----
    u16* attw = att + w * 32 * CPA;
#pragma unroll
    for (int mt = 0; mt < 8; ++mt) {
        f32x4 bv4 = *(const f32x4*)(bv + 16 * mt + 4 * g);
#pragma unroll
        for (int nt = 0; nt < 2; ++nt) {
            u16x4 ov;
#pragma unroll
            for (int r = 0; r < 4; ++r) ov[r] = f2b(o[mt][nt][r] * inv[nt] + bv4[r]);
            *(u16x4*)&attw[(16 * nt + l15) * CPA + 16 * mt + 4 * g] = ov;
        }
    }
    asm volatile("s_waitcnt lgkmcnt(0)" ::: "memory");
    __builtin_amdgcn_sched_barrier(0);

    // conv B-frags from own wave's att slice
    bf16x8 cb[4][2];
#pragma unroll
    for (int kk = 0; kk < 4; ++kk)
#pragma unroll
        for (int nt = 0; nt < 2; ++nt)
            cb[kk][nt] = *(const bf16x8*)&attw[(16 * nt + l15) * CPA + 32 * kk + 8 * g];

    // ---- conv + LIF in 4 c-quarters ----
    const int cl = t >> 3, n4 = (t & 7) * 4;  // LIF ownership
#pragma unroll
    for (int cr = 0; cr < 4; ++cr) {
#pragma unroll
        for (int oi = 0; oi < 2; ++oi) {
            const int ot = 2 * cr + oi;
            f32x4 ca[2];
#pragma unroll
            for (int nt = 0; nt < 2; ++nt) ca[nt] = *(const f32x4*)(bf + 16 * ot + 4 * g);
#pragma unroll
            for (int kk = 0; kk < 4; ++kk) {
                bf16x8 afr = ldA(WfB, ot, kk, l);
#pragma unroll
                for (int nt = 0; nt < 2; ++nt)
                    ca[nt] = __builtin_amdgcn_mfma_f32_16x16x32_bf16(afr, cb[kk][nt], ca[nt], 0, 0, 0);
            }
#pragma unroll
            for (int nt = 0; nt < 2; ++nt)
#pragma unroll
                for (int r = 0; r < 4; ++r)
                    convq[w * 32 * CQS + (16 * oi + 4 * g + r) * CQS + 16 * nt + l15] = ca[nt][r];
        }
        __syncthreads();
        // LIF over tt for c = 32*cr + cl, n = qx*32 + n4..n4+3
        f32x4 mem = {0.f, 0.f, 0.f, 0.f};
#pragma unroll
        for (int tt = 0; tt < 4; ++tt) {
            f32x4 x = *(const f32x4*)&convq[tt * 32 * CQS + cl * CQS + n4];
            f32x4 mv = mem * 0.5f + x;
            float4 sp;
            sp.x = (mv[0] > 1.0f) ? 1.0f : 0.0f; if (mv[0] > 1.0f) mv[0] = 0.f;
            sp.y = (mv[1] > 1.0f) ? 1.0f : 0.0f; if (mv[1] > 1.0f) mv[1] = 0.f;
            sp.z = (mv[2] > 1.0f) ? 1.0f : 0.0f; if (mv[2] > 1.0f) mv[2] = 0.f;
            sp.w = (mv[3] > 1.0f) ? 1.0f : 0.0f; if (mv[3] > 1.0f) mv[3] = 0.f;
            *(float4*)(out + ((size_t)(b * 4 + tt) * CC + 32 * cr + cl) * NN + qx * 32 + n4) = sp;
            mem = mv;
        }
        __syncthreads();
    }
}

extern "C" void kernel_launch(void* const* d_in, const int* in_sizes, int n_in,
                              void* d_out, int out_size, void* d_ws, size_t ws_size,
                              hipStream_t stream) {
    (void)in_sizes; (void)n_in; (void)out_size; (void)ws_size;
    const float* edge = (const float*)d_in[0];
    const float* dvs  = (const float*)d_in[1];
    const float* We = (const float*)d_in[2];
    const float* be = (const float*)d_in[3];
    const float* Wd = (const float*)d_in[4];
    const float* bd = (const float*)d_in[5];
    const float* Wq = (const float*)d_in[6];
    const float* bq = (const float*)d_in[7];
    const float* Wk = (const float*)d_in[8];
    const float* bk = (const float*)d_in[9];
    const float* Wv = (const float*)d_in[10];
    const float* bv = (const float*)d_in[11];
    const float* Wf = (const float*)d_in[12];
    const float* bf = (const float*)d_in[13];
    float* out = (float*)d_out;

    const size_t S = (size_t)BTOT * NN * CC;  // 4.19M elems
    u16* qT   = (u16*)d_ws;
    u16* kT   = qT + S;
    u16* vN   = kT + S;
    u16* WbAll = vN + S;                      // 6 * 16384 u16
    float* fbase = (float*)(WbAll + 6 * 16384);
    float* cvec  = fbase;                     // 3 * 128
    float* eexp  = cvec + 3 * CC;             // BTOT*NN
    float* partial = eexp + BTOT * NN;        // BTOT*16
    u16* WeB  = WbAll + 0 * 16384;
    u16* WdB  = WbAll + 1 * 16384;
    u16* WqeB = WbAll + 2 * 16384;
    u16* WkdB = WbAll + 3 * 16384;
    u16* WvdB = WbAll + 4 * 16384;
    u16* WfB  = WbAll + 5 * 16384;
    float* cq = cvec;
    float* ck = cvec + CC;
    float* cv = cvec + 2 * CC;

    k_prep<<<216, 256, 0, stream>>>(We, Wd, Wf, Wq, Wk, Wv, be, bd, WbAll, cvec);
    k_front<<<512, 256, 0, stream>>>(edge, dvs, WeB, WdB, WqeB, WkdB, WvdB,
                                     be, bd, bq, cq, ck, cv, eexp, partial, qT, kT, vN);
    k_attnf<<<256, 256, 0, stream>>>(qT, kT, vN, eexp, partial, bk, bv, WfB, bf, out);
}